// Round 10
// baseline (1333.749 us; speedup 1.0000x reference)
//
#include <hip/hip_runtime.h>
#include <hip/hip_bf16.h>
#include <stdint.h>

typedef unsigned short u16;
typedef __attribute__((ext_vector_type(8))) short bf16x8;
typedef __attribute__((ext_vector_type(4))) float f32x4;
typedef __attribute__((ext_vector_type(4))) u16 u16x4;
typedef __attribute__((ext_vector_type(4))) uint32_t u32x4;

__device__ __forceinline__ u16 f2bf(float f) {
  union { float f; uint32_t u; } v; v.f = f;
  uint32_t u = v.u + 0x7FFFu + ((v.u >> 16) & 1u);
  return (u16)(u >> 16);
}
__device__ __forceinline__ float bf2f(u16 h) {
  union { uint32_t u; float f; } v; v.u = ((uint32_t)h) << 16;
  return v.f;
}

// 1D XCD-chunked bijective remap (T1). Requires n%8==0.
__device__ __forceinline__ int xcd_swz(int hw, int n) {
  return (n & 7) ? hw : (hw & 7) * (n >> 3) + (hw >> 3);
}

__device__ __forceinline__ void gload_lds16(const void* g, void* l) {
  __builtin_amdgcn_global_load_lds(
      (const __attribute__((address_space(1))) void*)g,
      (__attribute__((address_space(3))) void*)l, 16, 0, 0);
}

// ---------------- cast f32 -> bf16 (vectorized x4) ----------------
__global__ __launch_bounds__(256) void cast_f32_bf16(const float* __restrict__ src,
                                                     u16* __restrict__ dst, int n4) {
  int i = blockIdx.x * 256 + threadIdx.x;
  if (i < n4) {
    float4 v = ((const float4*)src)[i];
    u16x4 o; o.x = f2bf(v.x); o.y = f2bf(v.y); o.z = f2bf(v.z); o.w = f2bf(v.w);
    ((u16x4*)dst)[i] = o;
  }
}

// ---------------- merged cast: all 5 weight tensors in ONE dispatch ----------------
__global__ __launch_bounds__(256)
void cast_all(const float* __restrict__ s0, const float* __restrict__ s1,
              const float* __restrict__ s2, const float* __restrict__ s3,
              const float* __restrict__ s4,
              u16* __restrict__ d0, u16* __restrict__ d1, u16* __restrict__ d2,
              u16* __restrict__ d3, u16* __restrict__ d4,
              long n0, long n1, long n2, long n3, long n4) {  // counts in f32x4 units
  long i = (long)blockIdx.x * 256 + threadIdx.x;
  const float* s; u16* d; long off;
  if (i < n0) { s = s0; d = d0; off = i; }
  else if (i < n0 + n1) { s = s1; d = d1; off = i - n0; }
  else if (i < n0 + n1 + n2) { s = s2; d = d2; off = i - n0 - n1; }
  else if (i < n0 + n1 + n2 + n3) { s = s3; d = d3; off = i - n0 - n1 - n2; }
  else if (i < n0 + n1 + n2 + n3 + n4) { s = s4; d = d4; off = i - n0 - n1 - n2 - n3; }
  else return;
  float4 v = ((const float4*)s)[off];
  u16x4 o; o.x = f2bf(v.x); o.y = f2bf(v.y); o.z = f2bf(v.z); o.w = f2bf(v.w);
  ((u16x4*)d)[off] = o;
}

// ---------------- im2col: image [B,3,512,512] -> [2048, 768] bf16 ----------------
__global__ __launch_bounds__(256) void im2col_kernel(const float* __restrict__ img,
                                                     u16* __restrict__ out) {
  int f = blockIdx.x * 256 + threadIdx.x;  // [0,768)
  int row = blockIdx.y;                    // [0,2048)
  int b = row >> 10, n = row & 1023, py = n >> 5, px = n & 31;
  int c = f >> 8, rem = f & 255, i = rem >> 4, j = rem & 15;
  float v = img[(((size_t)b * 3 + c) * 512 + py * 16 + i) * 512 + px * 16 + j];
  out[(size_t)row * 768 + f] = f2bf(v);
}

// ---------------- GEMM: 128x128 tile, BK=64, depth-2 counted-vmcnt pipeline ----------------
// T2 LDS XOR-swizzle; 2D/3D XCD rectangles (bijective; gx%XGX==0, gy%XGY==0).
// EPI: 1 = bias+GELU -> bf16 ; 4 = qkv bias+RoPE -> bf16 ; 5 = bf16 partial (split-K)
template <int EPI, int XGX, int XGY, int XGZ>
__global__ __launch_bounds__(256, 2)
void gemm_bt(const u16* __restrict__ A, const u16* __restrict__ W,
             const float* __restrict__ bias, void* __restrict__ outp,
             int M, int N, int K, int lda, int ldw) {
  constexpr int AB = 128 * 128;
  constexpr int BB = 128 * 128;
  constexpr int BUF = AB + BB;       // 32 KB
  constexpr int LOADS = BUF / 4096;  // 8 gload_lds16 per thread per stage
  __shared__ char smem[2 * BUF];     // 64 KB
  const int tid = threadIdx.x;
  const int lane = tid & 63;
  const int w = tid >> 6;
  const int qr = lane & 15;
  const int kg = lane >> 4;
  const int gx = gridDim.x, gy = gridDim.y;
  const int hw = blockIdx.x + gx * (blockIdx.y + gy * blockIdx.z);
  const int xcd = hw & 7, i = hw >> 3;
  const int sx = gx / XGX, sy = gy / XGY;
  const int cx = xcd % XGX, cy = (xcd / XGX) % XGY, cz = xcd / (XGX * XGY);
  const int bn = cx * sx + i % sx;
  const int rr_ = i / sx;
  const int bm = cy * sy + rr_ % sy;
  const int bz = cz * (gridDim.z / XGZ) + rr_ / sy;
  const int wr = (w >> 1) * 64;
  const int wc = (w & 1) * 64;
  const size_t arow0 = (size_t)bm * 128;
  const size_t wrow0 = (size_t)bn * 128;
  const u16* Ab = A + (size_t)bz * K;  // split-K k-offset
  const u16* Wb = W + (size_t)bz * K;

  f32x4 acc[4][4] = {};

  auto stage = [&](int buf, int kt) {
    char* As = smem + buf * BUF;
    char* Ws = As + AB;
#pragma unroll
    for (int r = 0; r < 4; ++r) {
      int o = r * 4096 + tid * 16;
      int row = o >> 7;
      int lc = (o & 127) ^ ((row & 7) << 4);
      gload_lds16(Ab + (arow0 + row) * lda + kt + (lc >> 1), As + o);
    }
#pragma unroll
    for (int r = 0; r < 4; ++r) {
      int o = r * 4096 + tid * 16;
      int row = o >> 7;
      int lc = (o & 127) ^ ((row & 7) << 4);
      gload_lds16(Wb + (wrow0 + row) * ldw + kt + (lc >> 1), Ws + o);
    }
  };

  const int nt = K >> 6;
  stage(0, 0);
  stage(1, 64);
  for (int t = 0; t < nt; ++t) {
    if (t + 1 < nt) {
      asm volatile("s_waitcnt vmcnt(%0)" :: "i"(LOADS) : "memory");
    } else {
      asm volatile("s_waitcnt vmcnt(0)" ::: "memory");
    }
    __builtin_amdgcn_s_barrier();
    const char* As = smem + (t & 1) * BUF;
    const char* Ws = As + AB;
    bf16x8 af[2][4], bfr[2][4];
#pragma unroll
    for (int m = 0; m < 4; ++m) {
      int row = wr + m * 16 + qr;
      af[0][m] = *(const bf16x8*)(As + row * 128 + ((kg * 16) ^ ((row & 7) << 4)));
    }
#pragma unroll
    for (int n = 0; n < 4; ++n) {
      int row = wc + n * 16 + qr;
      bfr[0][n] = *(const bf16x8*)(Ws + row * 128 + ((kg * 16) ^ ((row & 7) << 4)));
    }
    __builtin_amdgcn_sched_barrier(0);
#pragma unroll
    for (int m = 0; m < 4; ++m) {
      int row = wr + m * 16 + qr;
      af[1][m] = *(const bf16x8*)(As + row * 128 + ((64 + kg * 16) ^ ((row & 7) << 4)));
    }
#pragma unroll
    for (int n = 0; n < 4; ++n) {
      int row = wc + n * 16 + qr;
      bfr[1][n] = *(const bf16x8*)(Ws + row * 128 + ((64 + kg * 16) ^ ((row & 7) << 4)));
    }
    asm volatile("s_waitcnt lgkmcnt(8)" ::: "memory");
    __builtin_amdgcn_sched_barrier(0);
#pragma unroll
    for (int m = 0; m < 4; ++m)
#pragma unroll
      for (int n = 0; n < 4; ++n)
        acc[m][n] = __builtin_amdgcn_mfma_f32_16x16x32_bf16(af[0][m], bfr[0][n], acc[m][n], 0, 0, 0);
    asm volatile("s_waitcnt lgkmcnt(0)" ::: "memory");
    __builtin_amdgcn_sched_barrier(0);
    __builtin_amdgcn_s_barrier();
    if (t + 2 < nt) stage(t & 1, (t + 2) << 6);
#pragma unroll
    for (int m = 0; m < 4; ++m)
#pragma unroll
      for (int n = 0; n < 4; ++n)
        acc[m][n] = __builtin_amdgcn_mfma_f32_16x16x32_bf16(af[1][m], bfr[1][n], acc[m][n], 0, 0, 0);
  }

  const int r0 = bm * 128 + wr + kg * 4;
  const int c0 = bn * 128 + wc + qr;
  if constexpr (EPI == 4) {
    const int headbase = bn * 128 + wc;
    const bool isqk = headbase < 1536;
    const float linv = exp2f(-0.41524101186092122f * (float)qr);  // 100^(-qr/16)
    u16* outb = (u16*)outp;
#pragma unroll
    for (int m = 0; m < 4; ++m) {
#pragma unroll
      for (int j = 0; j < 4; ++j) {
        int row = r0 + m * 16 + j;
        int tok = row & 1023;
        float vs[4];
#pragma unroll
        for (int n = 0; n < 4; ++n) vs[n] = acc[m][n][j] + bias[c0 + n * 16];
        if (isqk) {
          float sy, cy, sxv, cxv;
          __sincosf((float)(tok >> 5) * linv, &sy, &cy);
          __sincosf((float)(tok & 31) * linv, &sxv, &cxv);
          float a0 = vs[0], a1 = vs[1], a2 = vs[2], a3 = vs[3];
          vs[0] = a0 * cy - a1 * sy;
          vs[1] = a1 * cy + a0 * sy;
          vs[2] = a2 * cxv - a3 * sxv;
          vs[3] = a3 * cxv + a2 * sxv;
        }
#pragma unroll
        for (int n = 0; n < 4; ++n)
          outb[(size_t)row * N + c0 + n * 16] = f2bf(vs[n]);
      }
    }
  } else if constexpr (EPI == 5) {  // bf16 split-K partial
    u16* outb = (u16*)outp + (size_t)bz * M * N;
#pragma unroll
    for (int m = 0; m < 4; ++m)
#pragma unroll
      for (int j = 0; j < 4; ++j) {
        int row = r0 + m * 16 + j;
#pragma unroll
        for (int n = 0; n < 4; ++n)
          outb[(size_t)row * N + c0 + n * 16] = f2bf(acc[m][n][j]);
      }
  } else {  // EPI == 1: bias + exact GELU -> bf16
    u16* outb = (u16*)outp;
#pragma unroll
    for (int m = 0; m < 4; ++m)
#pragma unroll
      for (int j = 0; j < 4; ++j) {
        int row = r0 + m * 16 + j;
#pragma unroll
        for (int n = 0; n < 4; ++n) {
          int col = c0 + n * 16;
          float v = acc[m][n][j] + bias[col];
          v = 0.5f * v * (1.0f + erff(v * 0.70710678118654752f));
          outb[(size_t)row * N + col] = f2bf(v);
        }
      }
  }
}

// ---------------- fused split-K(x2) reduce + residual(bf16) + LayerNorm ----------------
template <int FINAL>
__global__ __launch_bounds__(192)
void fuse_red_ln(const u16* __restrict__ parts, const float* __restrict__ bias,
                 const u16* __restrict__ resid, u16* __restrict__ xout,
                 void* __restrict__ lnout, const float* __restrict__ lw,
                 const float* __restrict__ lb, float eps) {
  if (FINAL && blockIdx.x >= 2048) {  // pos output tail
    int i = (blockIdx.x - 2048) * 192 + threadIdx.x;
    if (i < 4096) {
      int c = i & 1, n = (i >> 1) & 1023;
      ((float*)lnout)[(size_t)2048 * 768 + i] = (float)(c ? (n & 31) : (n >> 5));
    }
    return;
  }
  const int row = blockIdx.x, t = threadIdx.x;
  const int c0 = t * 4;
  constexpr size_t MN = (size_t)2048 * 768;
  const u16x4 pa = *(const u16x4*)(parts + (size_t)row * 768 + c0);
  const u16x4 pb = *(const u16x4*)(parts + MN + (size_t)row * 768 + c0);
  const f32x4 bi = *(const f32x4*)(bias + c0);
  f32x4 v;
#pragma unroll
  for (int j = 0; j < 4; ++j) v[j] = bf2f(pa[j]) + bf2f(pb[j]) + bi[j];
  if (resid) {
    const u16x4 rv = *(const u16x4*)(resid + (size_t)row * 768 + c0);
#pragma unroll
    for (int j = 0; j < 4; ++j) v[j] += bf2f(rv[j]);
  }
  if (xout) {
    u16x4 xo;
#pragma unroll
    for (int j = 0; j < 4; ++j) xo[j] = f2bf(v[j]);
    *(u16x4*)(xout + (size_t)row * 768 + c0) = xo;
#pragma unroll
    for (int j = 0; j < 4; ++j) v[j] = bf2f(xo[j]);
  }
  float s = (v[0] + v[1]) + (v[2] + v[3]);
  float sq = (v[0] * v[0] + v[1] * v[1]) + (v[2] * v[2] + v[3] * v[3]);
#pragma unroll
  for (int m = 1; m < 64; m <<= 1) {
    s += __shfl_xor(s, m);
    sq += __shfl_xor(sq, m);
  }
  __shared__ float red[6];
  int wv = t >> 6;
  if ((t & 63) == 0) { red[wv] = s; red[3 + wv] = sq; }
  __syncthreads();
  s = red[0] + red[1] + red[2];
  sq = red[3] + red[4] + red[5];
  float mean = s * (1.0f / 768.0f);
  float var = sq * (1.0f / 768.0f) - mean * mean;
  float rstd = rsqrtf(var + eps);
  const f32x4 lwv = *(const f32x4*)(lw + c0);
  const f32x4 lbv = *(const f32x4*)(lb + c0);
  if (FINAL) {
    f32x4 o;
#pragma unroll
    for (int j = 0; j < 4; ++j) o[j] = (v[j] - mean) * rstd * lwv[j] + lbv[j];
    *(f32x4*)((float*)lnout + (size_t)row * 768 + c0) = o;
  } else {
    u16x4 o;
#pragma unroll
    for (int j = 0; j < 4; ++j) o[j] = f2bf((v[j] - mean) * rstd * lwv[j] + lbv[j]);
    *(u16x4*)((u16*)lnout + (size_t)row * 768 + c0) = o;
  }
}

// ---------------- Flash attention, kv-split x2: 1536 blocks x 128 thr ----------------
// Each block: 32 q-rows x 8 kv-tiles (half the range). Writes UNNORMALIZED bf16
// O-partials + f32 l-partials; attn_combine merges halves. 32KB LDS -> 5 blk/CU.
__global__ __launch_bounds__(128)
void attn_kernel(const u16* __restrict__ qkv, u16* __restrict__ po, float* __restrict__ pl) {
  __shared__ char smem[32768];  // Ks0 | Ks1 | Vt0 | Vt1 (8KB each)
  const int tid = threadIdx.x, lane = tid & 63, w = tid >> 6;
  const int qr = lane & 15, kg = lane >> 4;
  const bool kgodd = (kg & 1) != 0;
  const int lid = xcd_swz(blockIdx.x, gridDim.x);  // 1536: 192-chunk per XCD
  const int kvh = lid & 1, qb = (lid >> 1) & 31, bh = lid >> 6;
  const int b = bh / 12, h = bh % 12;
  const int qrow0 = qb * 32 + w * 16;
  const int kt0 = kvh * 8, kt1 = kt0 + 8;
  const u16* kvb = qkv + (size_t)b * 1024 * 2304;

  bf16x8 aq[2];
  {
    const u16* qbase = qkv + ((size_t)(b * 1024 + qrow0 + qr)) * 2304 + h * 64;
    aq[0] = *(const bf16x8*)(qbase + kg * 8);
    aq[1] = *(const bf16x8*)(qbase + 32 + kg * 8);
#pragma unroll
    for (int r = 0; r < 2; ++r)
#pragma unroll
      for (int e = 0; e < 8; ++e)
        aq[r][e] = (short)f2bf(bf2f((u16)aq[r][e]) * 0.125f);
  }
  f32x4 oacc[4] = {};
  float lsum = 0.f;

  const int kvp = tid >> 3, dg = tid & 7;  // kvp in [0,16): pairs {kvp, kvp+16}
  bf16x8 va[2], vb[2];
  auto issueV = [&](int kt) {
#pragma unroll
    for (int rr = 0; rr < 2; ++rr) {
      int p = rr * 16 + kvp;
      const u16* vsrc = kvb + ((size_t)(kt * 64 + 2 * p)) * 2304 + 1536 + h * 64 + dg * 8;
      va[rr] = *(const bf16x8*)vsrc;
      vb[rr] = *(const bf16x8*)(vsrc + 2304);
    }
  };
  auto issueK = [&](int kt, int bsel) {
    char* Ks = smem + bsel * 8192;
#pragma unroll
    for (int r = 0; r < 4; ++r) {
      int off = r * 2048 + tid * 16;
      int kv = off >> 7;
      int db = (off ^ ((kv & 7) << 4)) & 127;
      gload_lds16(kvb + ((size_t)(kt * 64 + kv)) * 2304 + 768 + h * 64 + (db >> 1), Ks + off);
    }
  };
  auto writeV = [&](int bsel) {
    char* Vt = smem + 16384 + bsel * 8192;
#pragma unroll
    for (int rr = 0; rr < 2; ++rr) {
      int p = rr * 16 + kvp;
#pragma unroll
      for (int j = 0; j < 8; ++j) {
        int d = dg * 8 + j;
        uint32_t pk = (uint32_t)(u16)va[rr][j] | ((uint32_t)(u16)vb[rr][j] << 16);
        *(uint32_t*)(Vt + ((d * 128 + p * 4) ^ (((dg ^ j) & 7) << 4))) = pk;
      }
    }
  };

  issueV(kt0);
  issueK(kt0, 0);
  writeV(0);

  for (int kt = kt0; kt < kt1; ++kt) {
    const int c = kt & 1;
    asm volatile("s_waitcnt vmcnt(0) lgkmcnt(0)" ::: "memory");
    __builtin_amdgcn_s_barrier();
    if (kt + 1 < kt1) { issueV(kt + 1); issueK(kt + 1, c ^ 1); }

    const char* Ks = smem + c * 8192;
    const char* Vt = smem + 16384 + c * 8192;

    bf16x8 bk[2][4];
#pragma unroll
    for (int n = 0; n < 4; ++n) {
      int row = n * 16 + qr;
      bk[0][n] = *(const bf16x8*)(Ks + ((row * 128 + kg * 16) ^ ((row & 7) << 4)));
    }
    __builtin_amdgcn_sched_barrier(0);
#pragma unroll
    for (int n = 0; n < 4; ++n) {
      int row = n * 16 + qr;
      bk[1][n] = *(const bf16x8*)(Ks + ((row * 128 + 64 + kg * 16) ^ ((row & 7) << 4)));
    }
    f32x4 sa[4] = {};
    asm volatile("s_waitcnt lgkmcnt(4)" ::: "memory");
    __builtin_amdgcn_sched_barrier(0);
    __builtin_amdgcn_s_setprio(1);
#pragma unroll
    for (int n = 0; n < 4; ++n)
      sa[n] = __builtin_amdgcn_mfma_f32_16x16x32_bf16(bk[0][n], aq[0], sa[n], 0, 0, 0);
    asm volatile("s_waitcnt lgkmcnt(0)" ::: "memory");
    __builtin_amdgcn_sched_barrier(0);
#pragma unroll
    for (int n = 0; n < 4; ++n)
      sa[n] = __builtin_amdgcn_mfma_f32_16x16x32_bf16(bk[1][n], aq[1], sa[n], 0, 0, 0);
    __builtin_amdgcn_s_setprio(0);

    float pv[4][4];
    float ts = 0.f;
#pragma unroll
    for (int n = 0; n < 4; ++n)
#pragma unroll
      for (int j = 0; j < 4; ++j) {
        pv[n][j] = __expf(sa[n][j]);
        ts += pv[n][j];
      }
    lsum += ts;

    if (kt + 1 < kt1) writeV(c ^ 1);

    bf16x8 vf[2][4];
#pragma unroll
    for (int ks = 0; ks < 2; ++ks)
#pragma unroll
      for (int n = 0; n < 4; ++n) {
        int d = n * 16 + qr;
        vf[ks][n] = *(const bf16x8*)(Vt + ((d * 128 + ks * 64 + kg * 16) ^ ((((d >> 3) ^ (d & 7)) & 7) << 4)));
      }

    uint32_t pk0[4], pk1[4];
#pragma unroll
    for (int n = 0; n < 4; ++n) {
      asm("v_cvt_pk_bf16_f32 %0, %1, %2" : "=v"(pk0[n]) : "v"(pv[n][0]), "v"(pv[n][1]));
      asm("v_cvt_pk_bf16_f32 %0, %1, %2" : "=v"(pk1[n]) : "v"(pv[n][2]), "v"(pv[n][3]));
    }
    bf16x8 pb[2];
#pragma unroll
    for (int ks = 0; ks < 2; ++ks) {
      uint32_t A0 = pk0[ks * 2], B0 = pk0[ks * 2 + 1];
      uint32_t A1 = pk1[ks * 2], B1 = pk1[ks * 2 + 1];
      asm("v_permlane32_swap_b32 %0, %1" : "+v"(A0), "+v"(B0));
      asm("v_permlane32_swap_b32 %0, %1" : "+v"(A1), "+v"(B1));
      uint32_t sA0 = (uint32_t)__shfl_xor((int)A0, 16);
      uint32_t sA1 = (uint32_t)__shfl_xor((int)A1, 16);
      uint32_t sB0 = (uint32_t)__shfl_xor((int)B0, 16);
      uint32_t sB1 = (uint32_t)__shfl_xor((int)B1, 16);
      u32x4 dd;
      dd.x = kgodd ? sB0 : A0;
      dd.y = kgodd ? sB1 : A1;
      dd.z = kgodd ? B0 : sA0;
      dd.w = kgodd ? B1 : sA1;
      pb[ks] = __builtin_bit_cast(bf16x8, dd);
    }

    __builtin_amdgcn_s_setprio(1);
#pragma unroll
    for (int ks = 0; ks < 2; ++ks)
#pragma unroll
      for (int n = 0; n < 4; ++n)
        oacc[n] = __builtin_amdgcn_mfma_f32_16x16x32_bf16(vf[ks][n], pb[ks], oacc[n], 0, 0, 0);
    __builtin_amdgcn_s_setprio(0);
  }
  lsum += __shfl_xor(lsum, 16);
  lsum += __shfl_xor(lsum, 32);
  const size_t rowg = (size_t)(b * 1024 + qrow0 + qr);
  u16* pob = po + (size_t)kvh * 2048 * 768;
#pragma unroll
  for (int n = 0; n < 4; ++n) {
    u16x4 ov;
#pragma unroll
    for (int j = 0; j < 4; ++j) ov[j] = f2bf(oacc[n][j]);  // unnormalized
    *(u16x4*)(pob + rowg * 768 + h * 64 + n * 16 + kg * 4) = ov;
  }
  if (kg == 0) pl[(size_t)kvh * 2048 * 12 + rowg * 12 + h] = lsum;
}

// ---------------- combine attn kv-halves: o = (O0 + O1) / (l0 + l1) ----------------
__global__ __launch_bounds__(256)
void attn_combine(const u16* __restrict__ po, const float* __restrict__ pl,
                  u16* __restrict__ o) {
  int i = blockIdx.x * 256 + threadIdx.x;  // [0, 2048*192)
  int row = i / 192, rc = i - row * 192;
  int c0 = rc * 4, h = c0 >> 6;
  constexpr size_t MN = (size_t)2048 * 768;
  u16x4 a = *(const u16x4*)(po + (size_t)row * 768 + c0);
  u16x4 bq = *(const u16x4*)(po + MN + (size_t)row * 768 + c0);
  float inv = 1.0f / (pl[row * 12 + h] + pl[2048 * 12 + row * 12 + h]);
  u16x4 ov;
#pragma unroll
  for (int j = 0; j < 4; ++j) ov[j] = f2bf((bf2f(a[j]) + bf2f(bq[j])) * inv);
  *(u16x4*)(o + (size_t)row * 768 + c0) = ov;
}

extern "C" void kernel_launch(void* const* d_in, const int* in_sizes, int n_in,
                              void* d_out, int out_size, void* d_ws, size_t ws_size,
                              hipStream_t stream) {
  const float* image  = (const float*)d_in[0];
  const float* patch_w = (const float*)d_in[2];
  const float* patch_b = (const float*)d_in[3];
  const float* ln1_w = (const float*)d_in[4];
  const float* ln1_b = (const float*)d_in[5];
  const float* qkv_w = (const float*)d_in[6];
  const float* qkv_b = (const float*)d_in[7];
  const float* proj_w = (const float*)d_in[8];
  const float* proj_b = (const float*)d_in[9];
  const float* ln2_w = (const float*)d_in[10];
  const float* ln2_b = (const float*)d_in[11];
  const float* fc1_w = (const float*)d_in[12];
  const float* fc1_b = (const float*)d_in[13];
  const float* fc2_w = (const float*)d_in[14];
  const float* fc2_b = (const float*)d_in[15];
  const float* encn_w = (const float*)d_in[16];
  const float* encn_b = (const float*)d_in[17];

  char* ws = (char*)d_ws;
  size_t off = 0;
  auto alloc = [&](size_t bytes) {
    char* pr = ws + off;
    off += (bytes + 255) & ~(size_t)255;
    return pr;
  };

  u16* x      = (u16*)alloc((size_t)2048 * 768 * 2);   // bf16 residual stream
  u16* hbuf   = (u16*)alloc((size_t)2048 * 768 * 2);
  u16* qkvb   = (u16*)alloc((size_t)2048 * 2304 * 2);
  u16* obuf   = (u16*)alloc((size_t)2048 * 768 * 2);
  u16* h2     = (u16*)alloc((size_t)2048 * 3072 * 2);
  u16* wpb    = (u16*)alloc((size_t)768 * 768 * 2);
  u16* parts  = (u16*)alloc((size_t)2 * 2048 * 768 * 2);
  float* lparts = (float*)alloc((size_t)2 * 2048 * 12 * 4);

  const size_t wq_n = (size_t)12 * 2304 * 768;
  const size_t wp_n = (size_t)12 * 768 * 768;
  const size_t w1_n = (size_t)12 * 3072 * 768;
  const size_t w2_n = (size_t)12 * 3072 * 768;
  bool upfront = (off + 2 * (wq_n + wp_n + w1_n + w2_n) + (1u << 20)) <= ws_size;

  u16 *wq, *wp, *w1, *w2;
  if (upfront) {
    wq = (u16*)alloc(wq_n * 2);
    wp = (u16*)alloc(wp_n * 2);
    w1 = (u16*)alloc(w1_n * 2);
    w2 = (u16*)alloc(w2_n * 2);
  } else {
    wq = (u16*)alloc((size_t)2304 * 768 * 2);
    wp = (u16*)alloc((size_t)768 * 768 * 2);
    w1 = (u16*)alloc((size_t)3072 * 768 * 2);
    w2 = (u16*)alloc((size_t)3072 * 768 * 2);
  }

  auto cast = [&](const float* s, u16* d, size_t n) {
    int n4 = (int)(n / 4);
    cast_f32_bf16<<<(n4 + 255) / 256, 256, 0, stream>>>(s, d, n4);
  };

  if (upfront) {
    // one dispatch for all weight casts
    long n0 = (long)(wq_n / 4), n1 = (long)(wp_n / 4), n2 = (long)(w1_n / 4),
         n3 = (long)(w2_n / 4), n4 = (long)(768 * 768 / 4);
    long ntot = n0 + n1 + n2 + n3 + n4;
    cast_all<<<(int)((ntot + 255) / 256), 256, 0, stream>>>(
        qkv_w, proj_w, fc1_w, fc2_w, patch_w, wq, wp, w1, w2, wpb,
        n0, n1, n2, n3, n4);
  } else {
    cast(patch_w, wpb, (size_t)768 * 768);
  }

  // patch embed: split-K x2 + fused reduce -> x(bf16) AND layer-0 ln1 input
  im2col_kernel<<<dim3(3, 2048), 256, 0, stream>>>(image, hbuf);
  gemm_bt<5, 2, 2, 2><<<dim3(6, 16, 2), 256, 0, stream>>>(hbuf, wpb, nullptr, parts, 2048, 768, 384, 768, 768);
  fuse_red_ln<0><<<2048, 192, 0, stream>>>(parts, patch_b, nullptr, x, hbuf, ln1_w, ln1_b, 1e-5f);

  for (int L = 0; L < 12; ++L) {
    u16 *wqL, *wpL, *w1L, *w2L;
    if (upfront) {
      wqL = wq + (size_t)L * 2304 * 768;
      wpL = wp + (size_t)L * 768 * 768;
      w1L = w1 + (size_t)L * 3072 * 768;
      w2L = w2 + (size_t)L * 3072 * 768;
    } else {
      cast(qkv_w + (size_t)L * 2304 * 768, wq, (size_t)2304 * 768);
      cast(proj_w + (size_t)L * 768 * 768, wp, (size_t)768 * 768);
      cast(fc1_w + (size_t)L * 3072 * 768, w1, (size_t)3072 * 768);
      cast(fc2_w + (size_t)L * 768 * 3072, w2, (size_t)3072 * 768);
      wqL = wq; wpL = wp; w1L = w1; w2L = w2;
    }
    gemm_bt<4, 2, 4, 1><<<dim3(18, 16), 256, 0, stream>>>(hbuf, wqL, qkv_b + L * 2304, qkvb, 2048, 2304, 768, 768, 768);
    attn_kernel<<<1536, 128, 0, stream>>>(qkvb, parts, lparts);
    attn_combine<<<1536, 256, 0, stream>>>(parts, lparts, obuf);
    gemm_bt<5, 2, 2, 2><<<dim3(6, 16, 2), 256, 0, stream>>>(obuf, wpL, nullptr, parts, 2048, 768, 384, 768, 768);
    fuse_red_ln<0><<<2048, 192, 0, stream>>>(parts, proj_b + L * 768, x, x, hbuf,
                                             ln2_w + L * 768, ln2_b + L * 768, 1e-5f);
    gemm_bt<1, 2, 4, 1><<<dim3(24, 16), 256, 0, stream>>>(hbuf, w1L, fc1_b + L * 3072, h2, 2048, 3072, 768, 768, 768);
    gemm_bt<5, 2, 2, 2><<<dim3(6, 16, 2), 256, 0, stream>>>(h2, w2L, nullptr, parts, 2048, 768, 1536, 3072, 3072);
    if (L < 11) {
      fuse_red_ln<0><<<2048, 192, 0, stream>>>(parts, fc2_b + L * 768, x, x, hbuf,
                                               ln1_w + (L + 1) * 768, ln1_b + (L + 1) * 768, 1e-5f);
    } else {
      fuse_red_ln<1><<<2070, 192, 0, stream>>>(parts, fc2_b + L * 768, x, nullptr, (float*)d_out,
                                               encn_w, encn_b, 1e-6f);
    }
  }
}

// Round 11
// 1230.597 us; speedup vs baseline: 1.0838x; 1.0838x over previous
//
#include <hip/hip_runtime.h>
#include <hip/hip_bf16.h>
#include <stdint.h>

typedef unsigned short u16;
typedef __attribute__((ext_vector_type(8))) short bf16x8;
typedef __attribute__((ext_vector_type(4))) float f32x4;
typedef __attribute__((ext_vector_type(4))) u16 u16x4;
typedef __attribute__((ext_vector_type(8))) u16 u16x8;
typedef __attribute__((ext_vector_type(4))) uint32_t u32x4;

__device__ __forceinline__ u16 f2bf(float f) {
  union { float f; uint32_t u; } v; v.f = f;
  uint32_t u = v.u + 0x7FFFu + ((v.u >> 16) & 1u);
  return (u16)(u >> 16);
}
__device__ __forceinline__ float bf2f(u16 h) {
  union { uint32_t u; float f; } v; v.u = ((uint32_t)h) << 16;
  return v.f;
}

// 1D XCD-chunked bijective remap (T1). Requires n%8==0.
__device__ __forceinline__ int xcd_swz(int hw, int n) {
  return (n & 7) ? hw : (hw & 7) * (n >> 3) + (hw >> 3);
}

__device__ __forceinline__ void gload_lds16(const void* g, void* l) {
  __builtin_amdgcn_global_load_lds(
      (const __attribute__((address_space(1))) void*)g,
      (__attribute__((address_space(3))) void*)l, 16, 0, 0);
}

// ---------------- cast f32 -> bf16 (vectorized x4) ----------------
__global__ __launch_bounds__(256) void cast_f32_bf16(const float* __restrict__ src,
                                                     u16* __restrict__ dst, int n4) {
  int i = blockIdx.x * 256 + threadIdx.x;
  if (i < n4) {
    float4 v = ((const float4*)src)[i];
    u16x4 o; o.x = f2bf(v.x); o.y = f2bf(v.y); o.z = f2bf(v.z); o.w = f2bf(v.w);
    ((u16x4*)dst)[i] = o;
  }
}

// ---------------- merged cast, 8 elems/thread: 2x float4 load + 16B store ----------------
__global__ __launch_bounds__(256)
void cast8_all(const float* __restrict__ s0, const float* __restrict__ s1,
               const float* __restrict__ s2, const float* __restrict__ s3,
               const float* __restrict__ s4,
               u16* __restrict__ d0, u16* __restrict__ d1, u16* __restrict__ d2,
               u16* __restrict__ d3, u16* __restrict__ d4,
               long n0, long n1, long n2, long n3, long n4) {  // counts in 8-elem units
  long i = (long)blockIdx.x * 256 + threadIdx.x;
  const float* s; u16* d; long off;
  if (i < n0) { s = s0; d = d0; off = i; }
  else if (i < n0 + n1) { s = s1; d = d1; off = i - n0; }
  else if (i < n0 + n1 + n2) { s = s2; d = d2; off = i - n0 - n1; }
  else if (i < n0 + n1 + n2 + n3) { s = s3; d = d3; off = i - n0 - n1 - n2; }
  else if (i < n0 + n1 + n2 + n3 + n4) { s = s4; d = d4; off = i - n0 - n1 - n2 - n3; }
  else return;
  float4 a = ((const float4*)s)[off * 2];
  float4 b = ((const float4*)s)[off * 2 + 1];
  u16x8 o;
  o[0] = f2bf(a.x); o[1] = f2bf(a.y); o[2] = f2bf(a.z); o[3] = f2bf(a.w);
  o[4] = f2bf(b.x); o[5] = f2bf(b.y); o[6] = f2bf(b.z); o[7] = f2bf(b.w);
  ((u16x8*)d)[off] = o;
}

// ---------------- im2col: image [B,3,512,512] -> [2048, 768] bf16 ----------------
__global__ __launch_bounds__(256) void im2col_kernel(const float* __restrict__ img,
                                                     u16* __restrict__ out) {
  int f = blockIdx.x * 256 + threadIdx.x;  // [0,768)
  int row = blockIdx.y;                    // [0,2048)
  int b = row >> 10, n = row & 1023, py = n >> 5, px = n & 31;
  int c = f >> 8, rem = f & 255, i = rem >> 4, j = rem & 15;
  float v = img[(((size_t)b * 3 + c) * 512 + py * 16 + i) * 512 + px * 16 + j];
  out[(size_t)row * 768 + f] = f2bf(v);
}

// ---------------- GEMM: 128x128 tile, BK=64, depth-2 counted-vmcnt pipeline ----------------
// T2 LDS XOR-swizzle; 2D/3D XCD rectangles (bijective; gx%XGX==0, gy%XGY==0).
// EPI: 1 = bias+GELU -> bf16 ; 4 = qkv bias+RoPE -> bf16 ; 5 = bf16 partial (split-K)
template <int EPI, int XGX, int XGY, int XGZ>
__global__ __launch_bounds__(256, 2)
void gemm_bt(const u16* __restrict__ A, const u16* __restrict__ W,
             const float* __restrict__ bias, void* __restrict__ outp,
             int M, int N, int K, int lda, int ldw) {
  constexpr int AB = 128 * 128;
  constexpr int BB = 128 * 128;
  constexpr int BUF = AB + BB;       // 32 KB
  constexpr int LOADS = BUF / 4096;  // 8 gload_lds16 per thread per stage
  __shared__ char smem[2 * BUF];     // 64 KB
  const int tid = threadIdx.x;
  const int lane = tid & 63;
  const int w = tid >> 6;
  const int qr = lane & 15;
  const int kg = lane >> 4;
  const int gx = gridDim.x, gy = gridDim.y;
  const int hw = blockIdx.x + gx * (blockIdx.y + gy * blockIdx.z);
  const int xcd = hw & 7, i = hw >> 3;
  const int sx = gx / XGX, sy = gy / XGY;
  const int cx = xcd % XGX, cy = (xcd / XGX) % XGY, cz = xcd / (XGX * XGY);
  const int bn = cx * sx + i % sx;
  const int rr_ = i / sx;
  const int bm = cy * sy + rr_ % sy;
  const int bz = cz * (gridDim.z / XGZ) + rr_ / sy;
  const int wr = (w >> 1) * 64;
  const int wc = (w & 1) * 64;
  const size_t arow0 = (size_t)bm * 128;
  const size_t wrow0 = (size_t)bn * 128;
  const u16* Ab = A + (size_t)bz * K;  // split-K k-offset
  const u16* Wb = W + (size_t)bz * K;

  f32x4 acc[4][4] = {};

  auto stage = [&](int buf, int kt) {
    char* As = smem + buf * BUF;
    char* Ws = As + AB;
#pragma unroll
    for (int r = 0; r < 4; ++r) {
      int o = r * 4096 + tid * 16;
      int row = o >> 7;
      int lc = (o & 127) ^ ((row & 7) << 4);
      gload_lds16(Ab + (arow0 + row) * lda + kt + (lc >> 1), As + o);
    }
#pragma unroll
    for (int r = 0; r < 4; ++r) {
      int o = r * 4096 + tid * 16;
      int row = o >> 7;
      int lc = (o & 127) ^ ((row & 7) << 4);
      gload_lds16(Wb + (wrow0 + row) * ldw + kt + (lc >> 1), Ws + o);
    }
  };

  const int nt = K >> 6;
  stage(0, 0);
  stage(1, 64);
  for (int t = 0; t < nt; ++t) {
    if (t + 1 < nt) {
      asm volatile("s_waitcnt vmcnt(%0)" :: "i"(LOADS) : "memory");
    } else {
      asm volatile("s_waitcnt vmcnt(0)" ::: "memory");
    }
    __builtin_amdgcn_s_barrier();
    const char* As = smem + (t & 1) * BUF;
    const char* Ws = As + AB;
    bf16x8 af[2][4], bfr[2][4];
#pragma unroll
    for (int m = 0; m < 4; ++m) {
      int row = wr + m * 16 + qr;
      af[0][m] = *(const bf16x8*)(As + row * 128 + ((kg * 16) ^ ((row & 7) << 4)));
    }
#pragma unroll
    for (int n = 0; n < 4; ++n) {
      int row = wc + n * 16 + qr;
      bfr[0][n] = *(const bf16x8*)(Ws + row * 128 + ((kg * 16) ^ ((row & 7) << 4)));
    }
    __builtin_amdgcn_sched_barrier(0);
#pragma unroll
    for (int m = 0; m < 4; ++m) {
      int row = wr + m * 16 + qr;
      af[1][m] = *(const bf16x8*)(As + row * 128 + ((64 + kg * 16) ^ ((row & 7) << 4)));
    }
#pragma unroll
    for (int n = 0; n < 4; ++n) {
      int row = wc + n * 16 + qr;
      bfr[1][n] = *(const bf16x8*)(Ws + row * 128 + ((64 + kg * 16) ^ ((row & 7) << 4)));
    }
    asm volatile("s_waitcnt lgkmcnt(8)" ::: "memory");
    __builtin_amdgcn_sched_barrier(0);
#pragma unroll
    for (int m = 0; m < 4; ++m)
#pragma unroll
      for (int n = 0; n < 4; ++n)
        acc[m][n] = __builtin_amdgcn_mfma_f32_16x16x32_bf16(af[0][m], bfr[0][n], acc[m][n], 0, 0, 0);
    asm volatile("s_waitcnt lgkmcnt(0)" ::: "memory");
    __builtin_amdgcn_sched_barrier(0);
    __builtin_amdgcn_s_barrier();
    if (t + 2 < nt) stage(t & 1, (t + 2) << 6);
#pragma unroll
    for (int m = 0; m < 4; ++m)
#pragma unroll
      for (int n = 0; n < 4; ++n)
        acc[m][n] = __builtin_amdgcn_mfma_f32_16x16x32_bf16(af[1][m], bfr[1][n], acc[m][n], 0, 0, 0);
  }

  const int r0 = bm * 128 + wr + kg * 4;
  const int c0 = bn * 128 + wc + qr;
  if constexpr (EPI == 4) {
    const int headbase = bn * 128 + wc;
    const bool isqk = headbase < 1536;
    const float linv = exp2f(-0.41524101186092122f * (float)qr);  // 100^(-qr/16)
    u16* outb = (u16*)outp;
#pragma unroll
    for (int m = 0; m < 4; ++m) {
#pragma unroll
      for (int j = 0; j < 4; ++j) {
        int row = r0 + m * 16 + j;
        int tok = row & 1023;
        float vs[4];
#pragma unroll
        for (int n = 0; n < 4; ++n) vs[n] = acc[m][n][j] + bias[c0 + n * 16];
        if (isqk) {
          float sy, cy, sxv, cxv;
          __sincosf((float)(tok >> 5) * linv, &sy, &cy);
          __sincosf((float)(tok & 31) * linv, &sxv, &cxv);
          float a0 = vs[0], a1 = vs[1], a2 = vs[2], a3 = vs[3];
          vs[0] = a0 * cy - a1 * sy;
          vs[1] = a1 * cy + a0 * sy;
          vs[2] = a2 * cxv - a3 * sxv;
          vs[3] = a3 * cxv + a2 * sxv;
        }
#pragma unroll
        for (int n = 0; n < 4; ++n)
          outb[(size_t)row * N + c0 + n * 16] = f2bf(vs[n]);
      }
    }
  } else if constexpr (EPI == 5) {  // bf16 split-K partial
    u16* outb = (u16*)outp + (size_t)bz * M * N;
#pragma unroll
    for (int m = 0; m < 4; ++m)
#pragma unroll
      for (int j = 0; j < 4; ++j) {
        int row = r0 + m * 16 + j;
#pragma unroll
        for (int n = 0; n < 4; ++n)
          outb[(size_t)row * N + c0 + n * 16] = f2bf(acc[m][n][j]);
      }
  } else {  // EPI == 1: bias + exact GELU -> bf16
    u16* outb = (u16*)outp;
#pragma unroll
    for (int m = 0; m < 4; ++m)
#pragma unroll
      for (int j = 0; j < 4; ++j) {
        int row = r0 + m * 16 + j;
#pragma unroll
        for (int n = 0; n < 4; ++n) {
          int col = c0 + n * 16;
          float v = acc[m][n][j] + bias[col];
          v = 0.5f * v * (1.0f + erff(v * 0.70710678118654752f));
          outb[(size_t)row * N + col] = f2bf(v);
        }
      }
  }
}

// ---------------- fused split-K(x2) reduce + residual(bf16) + LayerNorm ----------------
template <int FINAL>
__global__ __launch_bounds__(192)
void fuse_red_ln(const u16* __restrict__ parts, const float* __restrict__ bias,
                 const u16* __restrict__ resid, u16* __restrict__ xout,
                 void* __restrict__ lnout, const float* __restrict__ lw,
                 const float* __restrict__ lb, float eps) {
  if (FINAL && blockIdx.x >= 2048) {  // pos output tail
    int i = (blockIdx.x - 2048) * 192 + threadIdx.x;
    if (i < 4096) {
      int c = i & 1, n = (i >> 1) & 1023;
      ((float*)lnout)[(size_t)2048 * 768 + i] = (float)(c ? (n & 31) : (n >> 5));
    }
    return;
  }
  const int row = blockIdx.x, t = threadIdx.x;
  const int c0 = t * 4;
  constexpr size_t MN = (size_t)2048 * 768;
  const u16x4 pa = *(const u16x4*)(parts + (size_t)row * 768 + c0);
  const u16x4 pb = *(const u16x4*)(parts + MN + (size_t)row * 768 + c0);
  const f32x4 bi = *(const f32x4*)(bias + c0);
  f32x4 v;
#pragma unroll
  for (int j = 0; j < 4; ++j) v[j] = bf2f(pa[j]) + bf2f(pb[j]) + bi[j];
  if (resid) {
    const u16x4 rv = *(const u16x4*)(resid + (size_t)row * 768 + c0);
#pragma unroll
    for (int j = 0; j < 4; ++j) v[j] += bf2f(rv[j]);
  }
  if (xout) {
    u16x4 xo;
#pragma unroll
    for (int j = 0; j < 4; ++j) xo[j] = f2bf(v[j]);
    *(u16x4*)(xout + (size_t)row * 768 + c0) = xo;
#pragma unroll
    for (int j = 0; j < 4; ++j) v[j] = bf2f(xo[j]);
  }
  float s = (v[0] + v[1]) + (v[2] + v[3]);
  float sq = (v[0] * v[0] + v[1] * v[1]) + (v[2] * v[2] + v[3] * v[3]);
#pragma unroll
  for (int m = 1; m < 64; m <<= 1) {
    s += __shfl_xor(s, m);
    sq += __shfl_xor(sq, m);
  }
  __shared__ float red[6];
  int wv = t >> 6;
  if ((t & 63) == 0) { red[wv] = s; red[3 + wv] = sq; }
  __syncthreads();
  s = red[0] + red[1] + red[2];
  sq = red[3] + red[4] + red[5];
  float mean = s * (1.0f / 768.0f);
  float var = sq * (1.0f / 768.0f) - mean * mean;
  float rstd = rsqrtf(var + eps);
  const f32x4 lwv = *(const f32x4*)(lw + c0);
  const f32x4 lbv = *(const f32x4*)(lb + c0);
  if (FINAL) {
    f32x4 o;
#pragma unroll
    for (int j = 0; j < 4; ++j) o[j] = (v[j] - mean) * rstd * lwv[j] + lbv[j];
    *(f32x4*)((float*)lnout + (size_t)row * 768 + c0) = o;
  } else {
    u16x4 o;
#pragma unroll
    for (int j = 0; j < 4; ++j) o[j] = f2bf((v[j] - mean) * rstd * lwv[j] + lbv[j]);
    *(u16x4*)((u16*)lnout + (size_t)row * 768 + c0) = o;
  }
}

// ---------------- Flash attention: 768 blocks x 128 thr (2 waves), QBLK=32 ----------------
// Full kv range per block; 3 blocks/CU exactly (balanced). Swapped MFMAs +
// in-register P repack; normalized bf16 output.
__global__ __launch_bounds__(128)
void attn_kernel(const u16* __restrict__ qkv, u16* __restrict__ o) {
  __shared__ char smem[32768];  // Ks0 | Ks1 | Vt0 | Vt1 (8KB each)
  const int tid = threadIdx.x, lane = tid & 63, w = tid >> 6;
  const int qr = lane & 15, kg = lane >> 4;
  const bool kgodd = (kg & 1) != 0;
  const int lid = xcd_swz(blockIdx.x, gridDim.x);  // 768: 96-chunk per XCD
  const int qb = lid & 31, bh = lid >> 5;
  const int b = bh / 12, h = bh % 12;
  const int qrow0 = qb * 32 + w * 16;
  const u16* kvb = qkv + (size_t)b * 1024 * 2304;

  bf16x8 aq[2];
  {
    const u16* qbase = qkv + ((size_t)(b * 1024 + qrow0 + qr)) * 2304 + h * 64;
    aq[0] = *(const bf16x8*)(qbase + kg * 8);
    aq[1] = *(const bf16x8*)(qbase + 32 + kg * 8);
#pragma unroll
    for (int r = 0; r < 2; ++r)
#pragma unroll
      for (int e = 0; e < 8; ++e)
        aq[r][e] = (short)f2bf(bf2f((u16)aq[r][e]) * 0.125f);
  }
  f32x4 oacc[4] = {};
  float lsum = 0.f;

  const int kvp = tid >> 3, dg = tid & 7;  // kvp in [0,16): pairs {kvp, kvp+16}
  bf16x8 va[2], vb[2];
  auto issueV = [&](int kt) {
#pragma unroll
    for (int rr = 0; rr < 2; ++rr) {
      int p = rr * 16 + kvp;
      const u16* vsrc = kvb + ((size_t)(kt * 64 + 2 * p)) * 2304 + 1536 + h * 64 + dg * 8;
      va[rr] = *(const bf16x8*)vsrc;
      vb[rr] = *(const bf16x8*)(vsrc + 2304);
    }
  };
  auto issueK = [&](int kt, int bsel) {
    char* Ks = smem + bsel * 8192;
#pragma unroll
    for (int r = 0; r < 4; ++r) {
      int off = r * 2048 + tid * 16;
      int kv = off >> 7;
      int db = (off ^ ((kv & 7) << 4)) & 127;
      gload_lds16(kvb + ((size_t)(kt * 64 + kv)) * 2304 + 768 + h * 64 + (db >> 1), Ks + off);
    }
  };
  auto writeV = [&](int bsel) {
    char* Vt = smem + 16384 + bsel * 8192;
#pragma unroll
    for (int rr = 0; rr < 2; ++rr) {
      int p = rr * 16 + kvp;
#pragma unroll
      for (int j = 0; j < 8; ++j) {
        int d = dg * 8 + j;
        uint32_t pk = (uint32_t)(u16)va[rr][j] | ((uint32_t)(u16)vb[rr][j] << 16);
        *(uint32_t*)(Vt + ((d * 128 + p * 4) ^ (((dg ^ j) & 7) << 4))) = pk;
      }
    }
  };

  issueV(0);
  issueK(0, 0);
  writeV(0);

  for (int kt = 0; kt < 16; ++kt) {
    const int c = kt & 1;
    asm volatile("s_waitcnt vmcnt(0) lgkmcnt(0)" ::: "memory");
    __builtin_amdgcn_s_barrier();
    if (kt + 1 < 16) { issueV(kt + 1); issueK(kt + 1, c ^ 1); }

    const char* Ks = smem + c * 8192;
    const char* Vt = smem + 16384 + c * 8192;

    bf16x8 bk[2][4];
#pragma unroll
    for (int n = 0; n < 4; ++n) {
      int row = n * 16 + qr;
      bk[0][n] = *(const bf16x8*)(Ks + ((row * 128 + kg * 16) ^ ((row & 7) << 4)));
    }
    __builtin_amdgcn_sched_barrier(0);
#pragma unroll
    for (int n = 0; n < 4; ++n) {
      int row = n * 16 + qr;
      bk[1][n] = *(const bf16x8*)(Ks + ((row * 128 + 64 + kg * 16) ^ ((row & 7) << 4)));
    }
    f32x4 sa[4] = {};
    asm volatile("s_waitcnt lgkmcnt(4)" ::: "memory");
    __builtin_amdgcn_sched_barrier(0);
    __builtin_amdgcn_s_setprio(1);
#pragma unroll
    for (int n = 0; n < 4; ++n)
      sa[n] = __builtin_amdgcn_mfma_f32_16x16x32_bf16(bk[0][n], aq[0], sa[n], 0, 0, 0);
    asm volatile("s_waitcnt lgkmcnt(0)" ::: "memory");
    __builtin_amdgcn_sched_barrier(0);
#pragma unroll
    for (int n = 0; n < 4; ++n)
      sa[n] = __builtin_amdgcn_mfma_f32_16x16x32_bf16(bk[1][n], aq[1], sa[n], 0, 0, 0);
    __builtin_amdgcn_s_setprio(0);

    float pv[4][4];
    float ts = 0.f;
#pragma unroll
    for (int n = 0; n < 4; ++n)
#pragma unroll
      for (int j = 0; j < 4; ++j) {
        pv[n][j] = __expf(sa[n][j]);
        ts += pv[n][j];
      }
    lsum += ts;

    if (kt + 1 < 16) writeV(c ^ 1);  // V(t+1) -> LDS under repack

    bf16x8 vf[2][4];
#pragma unroll
    for (int ks = 0; ks < 2; ++ks)
#pragma unroll
      for (int n = 0; n < 4; ++n) {
        int d = n * 16 + qr;
        vf[ks][n] = *(const bf16x8*)(Vt + ((d * 128 + ks * 64 + kg * 16) ^ ((((d >> 3) ^ (d & 7)) & 7) << 4)));
      }

    uint32_t pk0[4], pk1[4];
#pragma unroll
    for (int n = 0; n < 4; ++n) {
      asm("v_cvt_pk_bf16_f32 %0, %1, %2" : "=v"(pk0[n]) : "v"(pv[n][0]), "v"(pv[n][1]));
      asm("v_cvt_pk_bf16_f32 %0, %1, %2" : "=v"(pk1[n]) : "v"(pv[n][2]), "v"(pv[n][3]));
    }
    bf16x8 pb[2];
#pragma unroll
    for (int ks = 0; ks < 2; ++ks) {
      uint32_t A0 = pk0[ks * 2], B0 = pk0[ks * 2 + 1];
      uint32_t A1 = pk1[ks * 2], B1 = pk1[ks * 2 + 1];
      asm("v_permlane32_swap_b32 %0, %1" : "+v"(A0), "+v"(B0));
      asm("v_permlane32_swap_b32 %0, %1" : "+v"(A1), "+v"(B1));
      uint32_t sA0 = (uint32_t)__shfl_xor((int)A0, 16);
      uint32_t sA1 = (uint32_t)__shfl_xor((int)A1, 16);
      uint32_t sB0 = (uint32_t)__shfl_xor((int)B0, 16);
      uint32_t sB1 = (uint32_t)__shfl_xor((int)B1, 16);
      u32x4 dd;
      dd.x = kgodd ? sB0 : A0;
      dd.y = kgodd ? sB1 : A1;
      dd.z = kgodd ? B0 : sA0;
      dd.w = kgodd ? B1 : sA1;
      pb[ks] = __builtin_bit_cast(bf16x8, dd);
    }

    __builtin_amdgcn_s_setprio(1);
#pragma unroll
    for (int ks = 0; ks < 2; ++ks)
#pragma unroll
      for (int n = 0; n < 4; ++n)
        oacc[n] = __builtin_amdgcn_mfma_f32_16x16x32_bf16(vf[ks][n], pb[ks], oacc[n], 0, 0, 0);
    __builtin_amdgcn_s_setprio(0);
  }
  lsum += __shfl_xor(lsum, 16);
  lsum += __shfl_xor(lsum, 32);
  float inv = 1.0f / lsum;
  const size_t rowg = (size_t)(b * 1024 + qrow0 + qr);
#pragma unroll
  for (int n = 0; n < 4; ++n) {
    u16x4 ov;
#pragma unroll
    for (int j = 0; j < 4; ++j) ov[j] = f2bf(oacc[n][j] * inv);
    *(u16x4*)(o + rowg * 768 + h * 64 + n * 16 + kg * 4) = ov;
  }
}

extern "C" void kernel_launch(void* const* d_in, const int* in_sizes, int n_in,
                              void* d_out, int out_size, void* d_ws, size_t ws_size,
                              hipStream_t stream) {
  const float* image  = (const float*)d_in[0];
  const float* patch_w = (const float*)d_in[2];
  const float* patch_b = (const float*)d_in[3];
  const float* ln1_w = (const float*)d_in[4];
  const float* ln1_b = (const float*)d_in[5];
  const float* qkv_w = (const float*)d_in[6];
  const float* qkv_b = (const float*)d_in[7];
  const float* proj_w = (const float*)d_in[8];
  const float* proj_b = (const float*)d_in[9];
  const float* ln2_w = (const float*)d_in[10];
  const float* ln2_b = (const float*)d_in[11];
  const float* fc1_w = (const float*)d_in[12];
  const float* fc1_b = (const float*)d_in[13];
  const float* fc2_w = (const float*)d_in[14];
  const float* fc2_b = (const float*)d_in[15];
  const float* encn_w = (const float*)d_in[16];
  const float* encn_b = (const float*)d_in[17];

  char* ws = (char*)d_ws;
  size_t off = 0;
  auto alloc = [&](size_t bytes) {
    char* pr = ws + off;
    off += (bytes + 255) & ~(size_t)255;
    return pr;
  };

  u16* x      = (u16*)alloc((size_t)2048 * 768 * 2);   // bf16 residual stream
  u16* hbuf   = (u16*)alloc((size_t)2048 * 768 * 2);
  u16* qkvb   = (u16*)alloc((size_t)2048 * 2304 * 2);
  u16* obuf   = (u16*)alloc((size_t)2048 * 768 * 2);
  u16* h2     = (u16*)alloc((size_t)2048 * 3072 * 2);
  u16* wpb    = (u16*)alloc((size_t)768 * 768 * 2);
  u16* parts  = (u16*)alloc((size_t)2 * 2048 * 768 * 2);

  const size_t wq_n = (size_t)12 * 2304 * 768;
  const size_t wp_n = (size_t)12 * 768 * 768;
  const size_t w1_n = (size_t)12 * 3072 * 768;
  const size_t w2_n = (size_t)12 * 3072 * 768;
  bool upfront = (off + 2 * (wq_n + wp_n + w1_n + w2_n) + (1u << 20)) <= ws_size;

  u16 *wq, *wp, *w1, *w2;
  if (upfront) {
    wq = (u16*)alloc(wq_n * 2);
    wp = (u16*)alloc(wp_n * 2);
    w1 = (u16*)alloc(w1_n * 2);
    w2 = (u16*)alloc(w2_n * 2);
  } else {
    wq = (u16*)alloc((size_t)2304 * 768 * 2);
    wp = (u16*)alloc((size_t)768 * 768 * 2);
    w1 = (u16*)alloc((size_t)3072 * 768 * 2);
    w2 = (u16*)alloc((size_t)3072 * 768 * 2);
  }

  auto cast = [&](const float* s, u16* d, size_t n) {
    int n4 = (int)(n / 4);
    cast_f32_bf16<<<(n4 + 255) / 256, 256, 0, stream>>>(s, d, n4);
  };

  if (upfront) {
    // one dispatch, 8 elems/thread (2x float4 read + 16B store)
    long n0 = (long)(wq_n / 8), n1 = (long)(wp_n / 8), n2 = (long)(w1_n / 8),
         n3 = (long)(w2_n / 8), n4 = (long)(768 * 768 / 8);
    long ntot = n0 + n1 + n2 + n3 + n4;
    cast8_all<<<(int)((ntot + 255) / 256), 256, 0, stream>>>(
        qkv_w, proj_w, fc1_w, fc2_w, patch_w, wq, wp, w1, w2, wpb,
        n0, n1, n2, n3, n4);
  } else {
    cast(patch_w, wpb, (size_t)768 * 768);
  }

  // patch embed: split-K x2 + fused reduce -> x(bf16) AND layer-0 ln1 input
  im2col_kernel<<<dim3(3, 2048), 256, 0, stream>>>(image, hbuf);
  gemm_bt<5, 2, 2, 2><<<dim3(6, 16, 2), 256, 0, stream>>>(hbuf, wpb, nullptr, parts, 2048, 768, 384, 768, 768);
  fuse_red_ln<0><<<2048, 192, 0, stream>>>(parts, patch_b, nullptr, x, hbuf, ln1_w, ln1_b, 1e-5f);

  for (int L = 0; L < 12; ++L) {
    u16 *wqL, *wpL, *w1L, *w2L;
    if (upfront) {
      wqL = wq + (size_t)L * 2304 * 768;
      wpL = wp + (size_t)L * 768 * 768;
      w1L = w1 + (size_t)L * 3072 * 768;
      w2L = w2 + (size_t)L * 3072 * 768;
    } else {
      cast(qkv_w + (size_t)L * 2304 * 768, wq, (size_t)2304 * 768);
      cast(proj_w + (size_t)L * 768 * 768, wp, (size_t)768 * 768);
      cast(fc1_w + (size_t)L * 3072 * 768, w1, (size_t)3072 * 768);
      cast(fc2_w + (size_t)L * 768 * 3072, w2, (size_t)3072 * 768);
      wqL = wq; wpL = wp; w1L = w1; w2L = w2;
    }
    gemm_bt<4, 2, 4, 1><<<dim3(18, 16), 256, 0, stream>>>(hbuf, wqL, qkv_b + L * 2304, qkvb, 2048, 2304, 768, 768, 768);
    attn_kernel<<<768, 128, 0, stream>>>(qkvb, obuf);
    gemm_bt<5, 2, 2, 2><<<dim3(6, 16, 2), 256, 0, stream>>>(obuf, wpL, nullptr, parts, 2048, 768, 384, 768, 768);
    fuse_red_ln<0><<<2048, 192, 0, stream>>>(parts, proj_b + L * 768, x, x, hbuf,
                                             ln2_w + L * 768, ln2_b + L * 768, 1e-5f);
    gemm_bt<1, 2, 4, 1><<<dim3(24, 16), 256, 0, stream>>>(hbuf, w1L, fc1_b + L * 3072, h2, 2048, 3072, 768, 768, 768);
    gemm_bt<5, 2, 2, 2><<<dim3(6, 16, 2), 256, 0, stream>>>(h2, w2L, nullptr, parts, 2048, 768, 1536, 3072, 3072);
    if (L < 11) {
      fuse_red_ln<0><<<2048, 192, 0, stream>>>(parts, fc2_b + L * 768, x, x, hbuf,
                                               ln1_w + (L + 1) * 768, ln1_b + (L + 1) * 768, 1e-5f);
    } else {
      fuse_red_ln<1><<<2070, 192, 0, stream>>>(parts, fc2_b + L * 768, x, nullptr, (float*)d_out,
                                               encn_w, encn_b, 1e-6f);
    }
  }
}